// Round 6
// baseline (98.306 us; speedup 1.0000x reference)
//
#include <hip/hip_runtime.h>

#define TLEN 2048
#define BROWS 2048
#define NSHIFT 31
#define MAXSH 15
#define BLOCK 256
#define EPSF 1e-8f

// stride-12 padded LDS index: 8-float groups at 12-dword stride.
// 48*tid bytes -> 16B-aligned b128 reads; lane starts 12l mod 32 cover all
// 32 banks once per 8 lanes -> conflict-free b128.
__device__ __forceinline__ int padidx12(int k) { return 12 * (k >> 3) + (k & 7); }

// ---- DPP wave64 reductions (VALU pipe, zero DS ops) ----
template<int CTRL, int RMASK, bool BC>
__device__ __forceinline__ float dpp_mov(float v, float old) {
    return __int_as_float(__builtin_amdgcn_update_dpp(
        __float_as_int(old), __float_as_int(v), CTRL, RMASK, 0xF, BC));
}
// sum across 64 lanes; result valid in lane 63
__device__ __forceinline__ float wave_sum_dpp(float v) {
    v += dpp_mov<0x111, 0xF, true>(v, 0.f);   // row_shr:1
    v += dpp_mov<0x112, 0xF, true>(v, 0.f);   // row_shr:2
    v += dpp_mov<0x114, 0xF, true>(v, 0.f);   // row_shr:4
    v += dpp_mov<0x118, 0xF, true>(v, 0.f);   // row_shr:8  -> lane15 of each row
    v += dpp_mov<0x142, 0xA, true>(v, 0.f);   // row_bcast15 -> rows 1,3
    v += dpp_mov<0x143, 0xC, true>(v, 0.f);   // row_bcast31 -> lane63 = total
    return v;
}
// max across 64 lanes; result valid in lane 63
__device__ __forceinline__ float wave_max_dpp(float v) {
    v = fmaxf(v, dpp_mov<0x111, 0xF, false>(v, v));
    v = fmaxf(v, dpp_mov<0x112, 0xF, false>(v, v));
    v = fmaxf(v, dpp_mov<0x114, 0xF, false>(v, v));
    v = fmaxf(v, dpp_mov<0x118, 0xF, false>(v, v));
    v = fmaxf(v, dpp_mov<0x142, 0xA, false>(v, v));
    v = fmaxf(v, dpp_mov<0x143, 0xC, false>(v, v));
    return v;
}

// smem layout (floats):
//   [0, 3120)    : stride-12 padded ext targets (260 groups)
//   [3120, 3376) : wsum — 4 waves x 64 (only cols [0,31) written)
//   [3376, 3392) : rbuf — 4 waves x {sp,spp,st,stt}
__global__ void __launch_bounds__(BLOCK, 4)
pearson_fused_kernel(const float* __restrict__ preds,
                     const float* __restrict__ targets,
                     float* __restrict__ out)
{
    __shared__ float smem[3392];
    float* wsum = smem + 3120;
    float* rbuf = smem + 3376;

    const int tid  = threadIdx.x;
    const int wave = tid >> 6;
    const int lane = tid & 63;
    const int row  = blockIdx.x;
    const float* p_row = preds   + (size_t)row * TLEN;
    const float* t_row = targets + (size_t)row * TLEN;

    // ---- issue t loads FIRST (staging depends on them), then p loads.
    // p is needed only at the FMA loop; leaving it in flight (vmcnt>0) hides
    // its HBM latency behind staging + barrier + window reads.
    float4 tv0 = ((const float4*)t_row)[tid];
    float4 tv1 = ((const float4*)t_row)[tid + BLOCK];
    float hl = 0.f, hr = 0.f;
    if (tid < MAXSH)                      hl = t_row[TLEN - MAXSH + tid];
    else if (tid >= 32 && tid < 32 + MAXSH) hr = t_row[tid - 32];
    float4 pa = ((const float4*)p_row)[2 * tid];
    float4 pb = ((const float4*)p_row)[2 * tid + 1];

    // ---- stage ext targets into stride-12 LDS + t row sums ----
    {
        int k = tid * 4 + MAXSH;             // ext[k] = t[(k-15) mod T]
        smem[padidx12(k)]     = tv0.x;
        smem[padidx12(k + 1)] = tv0.y;
        smem[padidx12(k + 2)] = tv0.z;
        smem[padidx12(k + 3)] = tv0.w;
        k = (tid + BLOCK) * 4 + MAXSH;
        smem[padidx12(k)]     = tv1.x;
        smem[padidx12(k + 1)] = tv1.y;
        smem[padidx12(k + 2)] = tv1.z;
        smem[padidx12(k + 3)] = tv1.w;
        if (tid < MAXSH)                        smem[padidx12(tid)] = hl;
        else if (tid >= 32 && tid < 32 + MAXSH) smem[padidx12(TLEN + MAXSH + tid - 32)] = hr;
    }
    float st = 0.f, stt = 0.f;
    st += tv0.x + tv0.y + tv0.z + tv0.w;
    st += tv1.x + tv1.y + tv1.z + tv1.w;
    stt = fmaf(tv0.x, tv0.x, stt); stt = fmaf(tv0.y, tv0.y, stt);
    stt = fmaf(tv0.z, tv0.z, stt); stt = fmaf(tv0.w, tv0.w, stt);
    stt = fmaf(tv1.x, tv1.x, stt); stt = fmaf(tv1.y, tv1.y, stt);
    stt = fmaf(tv1.z, tv1.z, stt); stt = fmaf(tv1.w, tv1.w, stt);

    float pc[8];
    pc[0] = pa.x; pc[1] = pa.y; pc[2] = pa.z; pc[3] = pa.w;
    pc[4] = pb.x; pc[5] = pb.y; pc[6] = pb.z; pc[7] = pb.w;
    float sp = 0.f, spp = 0.f;
    #pragma unroll
    for (int i = 0; i < 8; ++i) { sp += pc[i]; spp = fmaf(pc[i], pc[i], spp); }

    // ---- stats: DPP reduce (VALU), lane63 writes one float4 ----
    sp  = wave_sum_dpp(sp);
    spp = wave_sum_dpp(spp);
    st  = wave_sum_dpp(st);
    stt = wave_sum_dpp(stt);
    if (lane == 63) {
        *(float4*)(rbuf + wave * 4) = make_float4(sp, spp, st, stt);
    }
    __syncthreads();   // staging (and rbuf) visible

    // ---- window: 9x ds_read_b128 + 1x b64, conflict-free, pinned to VGPRs ----
    float w[38];
    {
        const float* g = smem + 12 * tid;
        #pragma unroll
        for (int q = 0; q < 4; ++q) {
            float4 a = *(const float4*)(g + 12 * q);
            float4 b = *(const float4*)(g + 12 * q + 4);
            w[8*q + 0] = a.x; w[8*q + 1] = a.y; w[8*q + 2] = a.z; w[8*q + 3] = a.w;
            w[8*q + 4] = b.x; w[8*q + 5] = b.y; w[8*q + 6] = b.z; w[8*q + 7] = b.w;
        }
        float4 c = *(const float4*)(g + 48);
        float2 e = *(const float2*)(g + 52);
        w[32] = c.x; w[33] = c.y; w[34] = c.z; w[35] = c.w;
        w[36] = e.x; w[37] = e.y;
        // compiler barrier: stops the ds_reads sinking into the FMA loop
        // (R3 showed the sunk form: VGPR 44, ~248 scalar ds_read_b32/thread)
        #pragma unroll
        for (int d = 0; d < 38; ++d) asm volatile("" : "+v"(w[d]));
    }

    // ---- 31 raw circular dots: acc[s] = sum_m pc[m] * ext[8*tid + m + s] ----
    float acc[NSHIFT];
    #pragma unroll
    for (int s = 0; s < NSHIFT; ++s) acc[s] = 0.f;
    #pragma unroll
    for (int m = 0; m < 8; ++m) {
        #pragma unroll
        for (int s = 0; s < NSHIFT; ++s) acc[s] = fmaf(pc[m], w[m + s], acc[s]);
    }

    // ---- in-wave DPP reduce of all 31 shifts; lane63 holds the wave sums ----
    #pragma unroll
    for (int s = 0; s < NSHIFT; ++s) acc[s] = wave_sum_dpp(acc[s]);
    if (lane == 63) {
        float* dst = wsum + wave * 64;
        *(float4*)(dst +  0) = make_float4(acc[0],  acc[1],  acc[2],  acc[3]);
        *(float4*)(dst +  4) = make_float4(acc[4],  acc[5],  acc[6],  acc[7]);
        *(float4*)(dst +  8) = make_float4(acc[8],  acc[9],  acc[10], acc[11]);
        *(float4*)(dst + 12) = make_float4(acc[12], acc[13], acc[14], acc[15]);
        *(float4*)(dst + 16) = make_float4(acc[16], acc[17], acc[18], acc[19]);
        *(float4*)(dst + 20) = make_float4(acc[20], acc[21], acc[22], acc[23]);
        *(float4*)(dst + 24) = make_float4(acc[24], acc[25], acc[26], acc[27]);
        *(float2*)(dst + 28) = make_float2(acc[28], acc[29]);
        dst[30] = acc[30];
    }
    __syncthreads();

    // ---- final: wave 0 only; lane s (<31) owns shift s ----
    if (wave == 0) {
        float dot = wsum[lane] + wsum[64 + lane] + wsum[128 + lane] + wsum[192 + lane];
        float4 r0 = *(const float4*)(rbuf + 0);
        float4 r1 = *(const float4*)(rbuf + 4);
        float4 r2 = *(const float4*)(rbuf + 8);
        float4 r3 = *(const float4*)(rbuf + 12);
        float SP  = r0.x + r1.x + r2.x + r3.x;
        float SPP = r0.y + r1.y + r2.y + r3.y;
        float ST  = r0.z + r1.z + r2.z + r3.z;
        float STT = r0.w + r1.w + r2.w + r3.w;
        const float invT = 1.0f / TLEN;
        float mp = SP * invT, mt = ST * invT;
        float varp = SPP - (float)TLEN * mp * mp;
        float vart = STT - (float)TLEN * mt * mt;
        float corr = (float)TLEN * mp * mt;
        float pear = (dot - corr) * rsqrtf((varp + EPSF) * (vart + EPSF));
        float v = (lane < NSHIFT) ? pear : -3.0e38f;   // mask garbage lanes
        v = wave_max_dpp(v);
        if (lane == 63) {
            float best = fmaxf(v, -1.0f);
            // bare device-scope atomic: coherent by itself (no fence needed).
            // sum over rows of (1 - best)/BROWS == 1 - mean(best).
            atomicAdd(out, (1.0f - best) * (1.0f / (float)BROWS));
        }
    }
}

extern "C" void kernel_launch(void* const* d_in, const int* in_sizes, int n_in,
                              void* d_out, int out_size, void* d_ws, size_t ws_size,
                              hipStream_t stream) {
    const float* preds   = (const float*)d_in[0];
    const float* targets = (const float*)d_in[1];
    float* out = (float*)d_out;
    hipMemsetAsync(out, 0, sizeof(float), stream);   // d_out is re-poisoned each iter
    pearson_fused_kernel<<<BROWS, BLOCK, 0, stream>>>(preds, targets, out);
}